// Round 2
// baseline (986.474 us; speedup 1.0000x reference)
//
#include <hip/hip_runtime.h>
#include <hip/hip_bf16.h>

typedef unsigned short u16;
typedef __bf16 bf16x8 __attribute__((ext_vector_type(8)));
typedef unsigned short ushort8v __attribute__((ext_vector_type(8)));
typedef float f32x4 __attribute__((ext_vector_type(4)));

#define B_ 4
#define T_ 2048
#define C_ 2048
#define H_ 32
#define S_ 64
#define NCH 16
#define CHL 128

__device__ __forceinline__ u16 f2bf(float x) {
  unsigned int u = __float_as_uint(x);
  unsigned int r = (u + 0x7fffu + ((u >> 16) & 1u)) >> 16;
  return (u16)r;
}
__device__ __forceinline__ float bf2f(u16 x) {
  return __uint_as_float(((unsigned int)x) << 16);
}
__device__ __forceinline__ float rdlane(float v, int l) {
  return __uint_as_float(__builtin_amdgcn_readlane(__float_as_uint(v), l));
}
__device__ __forceinline__ void gload_lds16(const void* g, void* l) {
  __builtin_amdgcn_global_load_lds(
      (const __attribute__((address_space(1))) void*)g,
      (__attribute__((address_space(3))) void*)l, 16, 0, 0);
}

// ---------------- mix + cast to bf16 ----------------
__global__ __launch_bounds__(256) void mix_cast_kernel(
    const float* __restrict__ hidden, const float* __restrict__ mixp,
    u16* __restrict__ out) {
  int idx = blockIdx.x * 256 + threadIdx.x;  // float4 index, total B*T*C/4
  int c4 = idx & 511;                        // C/4 = 512
  int bt = idx >> 9;
  int t = bt & (T_ - 1);
  float4 h = reinterpret_cast<const float4*>(hidden)[idx];
  float4 m = reinterpret_cast<const float4*>(mixp)[c4];
  float4 sh = make_float4(0.f, 0.f, 0.f, 0.f);
  if (t != 0) sh = reinterpret_cast<const float4*>(hidden)[idx - 512];
  ushort4 o;
  o.x = f2bf(h.x * m.x + sh.x * (1.f - m.x));
  o.y = f2bf(h.y * m.y + sh.y * (1.f - m.y));
  o.z = f2bf(h.z * m.z + sh.z * (1.f - m.z));
  o.w = f2bf(h.w * m.w + sh.w * (1.f - m.w));
  reinterpret_cast<ushort4*>(out)[idx] = o;
}

// ---------------- fp32 -> bf16 weight cast ----------------
__global__ __launch_bounds__(256) void conv_bf16_kernel(
    const float* __restrict__ in, u16* __restrict__ out, int n4) {
  int i = blockIdx.x * 256 + threadIdx.x;
  if (i >= n4) return;
  float4 v = reinterpret_cast<const float4*>(in)[i];
  ushort4 o;
  o.x = f2bf(v.x); o.y = f2bf(v.y); o.z = f2bf(v.z); o.w = f2bf(v.w);
  reinterpret_cast<ushort4*>(out)[i] = o;
}

// ---------------- bf16 GEMM: C[M,N] = A[M,K] * B[N,K]^T ----------------
// m97 structure: 128x128 tile, BK=64, 4 waves (2x2), global_load_lds w16.
template <typename OT>
__global__ __launch_bounds__(256) void gemm_bt(
    const u16* __restrict__ A, const u16* __restrict__ Bm,
    OT* __restrict__ C, int M, int N, int K) {
  __shared__ u16 As[128 * 64];
  __shared__ u16 Bs[128 * 64];
  int tid = threadIdx.x, lane = tid & 63, wid = tid >> 6;
  int nbn = N >> 7;
  int nwg = gridDim.x;
  int bid = blockIdx.x;
  int cpx = nwg >> 3;  // grid is a multiple of 8 here
  int swz = (bid & 7) * cpx + (bid >> 3);
  int bm = swz / nbn, bn = swz % nbn;
  int wr = wid >> 1, wc = wid & 1;

  f32x4 acc[4][4];
#pragma unroll
  for (int m = 0; m < 4; m++)
#pragma unroll
    for (int n = 0; n < 4; n++) acc[m][n] = (f32x4){0.f, 0.f, 0.f, 0.f};

  int row_in = lane >> 3;  // 0..7
  int col8 = lane & 7;     // 0..7 (x8 bf16 = 16B)
  const u16* Abase = A + ((size_t)(bm * 128 + wid * 32 + row_in)) * K + col8 * 8;
  const u16* Bbase = Bm + ((size_t)(bn * 128 + wid * 32 + row_in)) * K + col8 * 8;

  for (int kt = 0; kt < K; kt += 64) {
#pragma unroll
    for (int it = 0; it < 4; ++it) {
      gload_lds16(Abase + (size_t)(it * 8) * K + kt, &As[(wid * 32 + it * 8) * 64]);
      gload_lds16(Bbase + (size_t)(it * 8) * K + kt, &Bs[(wid * 32 + it * 8) * 64]);
    }
    __syncthreads();
#pragma unroll
    for (int kk = 0; kk < 2; ++kk) {
      int koff = kk * 32 + (lane >> 4) * 8;
      bf16x8 af[4], bfr[4];
      int rowa = wr * 64 + (lane & 15);
      int rowb = wc * 64 + (lane & 15);
#pragma unroll
      for (int m = 0; m < 4; m++) {
        ushort8v t8 = *reinterpret_cast<const ushort8v*>(&As[(rowa + m * 16) * 64 + koff]);
        af[m] = __builtin_bit_cast(bf16x8, t8);
      }
#pragma unroll
      for (int n = 0; n < 4; n++) {
        ushort8v t8 = *reinterpret_cast<const ushort8v*>(&Bs[(rowb + n * 16) * 64 + koff]);
        bfr[n] = __builtin_bit_cast(bf16x8, t8);
      }
#pragma unroll
      for (int m = 0; m < 4; m++)
#pragma unroll
        for (int n = 0; n < 4; n++)
          acc[m][n] = __builtin_amdgcn_mfma_f32_16x16x32_bf16(af[m], bfr[n], acc[m][n], 0, 0, 0);
    }
    __syncthreads();
  }

  int crow0 = bm * 128 + wr * 64 + (lane >> 4) * 4;
  int ccol = bn * 128 + wc * 64 + (lane & 15);
#pragma unroll
  for (int m = 0; m < 4; m++) {
#pragma unroll
    for (int q = 0; q < 4; q++) {
      OT* cp = C + (size_t)(crow0 + m * 16 + q) * N + ccol;
#pragma unroll
      for (int n = 0; n < 4; n++) {
        if constexpr (sizeof(OT) == 2)
          cp[n * 16] = (OT)f2bf(acc[m][n][q]);
        else
          cp[n * 16] = (OT)acc[m][n][q];
      }
    }
  }
}

// ---------------- scan phase 1: per-chunk summaries from zero state ----------------
__global__ __launch_bounds__(256) void scan_phase1(
    const u16* __restrict__ Kb, const u16* __restrict__ Vb,
    const float* __restrict__ td, float* __restrict__ chunks) {
  int lane = threadIdx.x & 63;
  int gw = (blockIdx.x * 256 + threadIdx.x) >> 6;  // 0..2047
  int c = gw & 15, bh = gw >> 4;
  int h = bh & 31, b = bh >> 5;
  const float* tdh = td + h * 64;
  float wreg[64];
#pragma unroll
  for (int s = 0; s < 64; s++) wreg[s] = __expf(-__expf(tdh[s]));
  float st[64];
#pragma unroll
  for (int s = 0; s < 64; s++) st[s] = 0.f;
  size_t base = ((size_t)b * T_ + (size_t)c * CHL) * C_ + h * 64 + lane;
  const u16* Kp = Kb + base;
  const u16* Vp = Vb + base;
  float kcur = bf2f(Kp[0]), vcur = bf2f(Vp[0]);
  for (int t = 0; t < CHL; t++) {
    float kn = 0.f, vn = 0.f;
    if (t + 1 < CHL) { kn = bf2f(Kp[(size_t)(t + 1) * C_]); vn = bf2f(Vp[(size_t)(t + 1) * C_]); }
#pragma unroll
    for (int s = 0; s < 64; s++) {
      float ks = rdlane(kcur, s);
      st[s] = fmaf(wreg[s], st[s], ks * vcur);
    }
    kcur = kn; vcur = vn;
  }
  float* outp = chunks + (((size_t)c * B_ + b) * H_ + h) * 4096 + lane;
#pragma unroll
  for (int s = 0; s < 64; s++) outp[s * 64] = st[s];
}

// ---------------- scan phase 2: propagate boundary states across chunks ----------------
__global__ __launch_bounds__(256) void scan_phase2(
    const float* __restrict__ st0, const float* __restrict__ td,
    float* __restrict__ chunks, float* __restrict__ state_out) {
  int idx = blockIdx.x * 256 + threadIdx.x;  // < 524288 over [b][h][s][d]
  int h = (idx >> 12) & 31;
  int s = (idx >> 6) & 63;
  float wL = __expf(-128.f * __expf(td[h * 64 + s]));  // w^128
  float st = st0[idx];
#pragma unroll
  for (int cc = 0; cc < 16; cc++) {
    size_t off = (size_t)cc * 524288 + idx;
    float sc = chunks[off];
    chunks[off] = st;  // boundary state at START of chunk cc
    st = fmaf(wL, st, sc);
  }
  state_out[idx] = st;
}

// ---------------- scan phase 3: outputs + fused groupnorm/ln/silu(gate) -> bf16 ----------------
__global__ __launch_bounds__(256) void scan_phase3(
    const u16* __restrict__ Rb, const u16* __restrict__ Kb,
    const u16* __restrict__ Vb, const float* __restrict__ td,
    const float* __restrict__ tf, const float* __restrict__ chunks,
    const u16* __restrict__ Gb, const float* __restrict__ lnw,
    const float* __restrict__ lnb, u16* __restrict__ Y) {
  int lane = threadIdx.x & 63;
  int gw = (blockIdx.x * 256 + threadIdx.x) >> 6;
  int c = gw & 15, bh = gw >> 4;
  int h = bh & 31, b = bh >> 5;
  const float* tdh = td + h * 64;
  float wreg[64];
#pragma unroll
  for (int s = 0; s < 64; s++) wreg[s] = __expf(-__expf(tdh[s]));
  float u_own = tf[h * 64 + lane];
  float lw = lnw[h * 64 + lane];
  float lb = lnb[h * 64 + lane];
  float st[64];
  const float* cp = chunks + (((size_t)c * B_ + b) * H_ + h) * 4096 + lane;
#pragma unroll
  for (int s = 0; s < 64; s++) st[s] = cp[s * 64];
  size_t base = ((size_t)b * T_ + (size_t)c * CHL) * C_ + h * 64 + lane;
  const u16* Rp = Rb + base;
  const u16* Kp = Kb + base;
  const u16* Vp = Vb + base;
  const u16* Gp = Gb + base;
  u16* Yp = Y + base;
  float rcur = bf2f(Rp[0]), kcur = bf2f(Kp[0]), vcur = bf2f(Vp[0]);
  for (int t = 0; t < CHL; t++) {
    float rn = 0.f, kn = 0.f, vn = 0.f;
    if (t + 1 < CHL) {
      rn = bf2f(Rp[(size_t)(t + 1) * C_]);
      kn = bf2f(Kp[(size_t)(t + 1) * C_]);
      vn = bf2f(Vp[(size_t)(t + 1) * C_]);
    }
    float p = rcur * u_own * kcur;
#pragma unroll
    for (int off = 32; off >= 1; off >>= 1) p += __shfl_xor(p, off);
    float acc = 0.f;
#pragma unroll
    for (int s = 0; s < 64; s++) {
      float rs = rdlane(rcur, s);
      float ks = rdlane(kcur, s);
      acc = fmaf(rs, st[s], acc);
      st[s] = fmaf(wreg[s], st[s], ks * vcur);
    }
    float o = fmaf(p, vcur, acc);
    // fused groupnorm over the wave's 64 lanes (= one (bt,h) group)
    float x = o * 0.125f;
    float sum = x;
#pragma unroll
    for (int off = 32; off >= 1; off >>= 1) sum += __shfl_xor(sum, off);
    float mean = sum * (1.f / 64.f);
    float d = x - mean;
    float v2 = d * d;
#pragma unroll
    for (int off = 32; off >= 1; off >>= 1) v2 += __shfl_xor(v2, off);
    float var = v2 * (1.f / 64.f);
    float xn = d * rsqrtf(var + 1e-5f);
    float g = bf2f(Gp[(size_t)t * C_]);
    float sg = g / (1.f + __expf(-g));
    Yp[(size_t)t * C_] = f2bf((xn * lw + lb) * sg);
    rcur = rn; kcur = kn; vcur = vn;
  }
}

extern "C" void kernel_launch(void* const* d_in, const int* in_sizes, int n_in,
                              void* d_out, int out_size, void* d_ws, size_t ws_size,
                              hipStream_t stream) {
  const float* hidden = (const float*)d_in[0];
  const float* state0 = (const float*)d_in[1];
  const float* td = (const float*)d_in[2];
  const float* tf = (const float*)d_in[3];
  const float* mk = (const float*)d_in[4];
  const float* mv = (const float*)d_in[5];
  const float* mr = (const float*)d_in[6];
  const float* mg = (const float*)d_in[7];
  const float* kw = (const float*)d_in[8];
  const float* vw = (const float*)d_in[9];
  const float* rw = (const float*)d_in[10];
  const float* gw = (const float*)d_in[11];
  const float* ow = (const float*)d_in[12];
  const float* lnw = (const float*)d_in[13];
  const float* lnb = (const float*)d_in[14];

  float* out = (float*)d_out;
  float* state_f = out + (size_t)B_ * T_ * C_;

  // workspace layout: ~210 MiB total (was 392 MiB -> suspected d_ws overflow)
  char* ws = (char*)d_ws;
  u16* mixA = (u16*)ws;    ws += (size_t)B_ * T_ * C_ * 2;  // 33.5MB (A for each GEMM; reused for gn output)
  u16* wb = (u16*)ws;      ws += (size_t)C_ * C_ * 2;       // 8.4MB
  u16* rb = (u16*)ws;      ws += (size_t)B_ * T_ * C_ * 2;  // 33.5MB
  u16* kb = (u16*)ws;      ws += (size_t)B_ * T_ * C_ * 2;
  u16* vb = (u16*)ws;      ws += (size_t)B_ * T_ * C_ * 2;
  u16* gb = (u16*)ws;      ws += (size_t)B_ * T_ * C_ * 2;
  float* chunks = (float*)ws;  ws += (size_t)NCH * B_ * H_ * S_ * S_ * 4;  // 33.5MB

  dim3 blk(256);
  int mixGrid = (B_ * T_ * C_ / 4) / 256;       // 16384
  int convN4 = C_ * C_ / 4;                     // 1048576
  int convGrid = convN4 / 256;                  // 4096
  int gemmGrid = (B_ * T_ / 128) * (C_ / 128);  // 1024

  // receptance
  mix_cast_kernel<<<mixGrid, blk, 0, stream>>>(hidden, mr, mixA);
  conv_bf16_kernel<<<convGrid, blk, 0, stream>>>(rw, wb, convN4);
  gemm_bt<u16><<<gemmGrid, blk, 0, stream>>>(mixA, wb, rb, B_ * T_, C_, C_);
  // key
  mix_cast_kernel<<<mixGrid, blk, 0, stream>>>(hidden, mk, mixA);
  conv_bf16_kernel<<<convGrid, blk, 0, stream>>>(kw, wb, convN4);
  gemm_bt<u16><<<gemmGrid, blk, 0, stream>>>(mixA, wb, kb, B_ * T_, C_, C_);
  // value
  mix_cast_kernel<<<mixGrid, blk, 0, stream>>>(hidden, mv, mixA);
  conv_bf16_kernel<<<convGrid, blk, 0, stream>>>(vw, wb, convN4);
  gemm_bt<u16><<<gemmGrid, blk, 0, stream>>>(mixA, wb, vb, B_ * T_, C_, C_);
  // gate
  mix_cast_kernel<<<mixGrid, blk, 0, stream>>>(hidden, mg, mixA);
  conv_bf16_kernel<<<convGrid, blk, 0, stream>>>(gw, wb, convN4);
  gemm_bt<u16><<<gemmGrid, blk, 0, stream>>>(mixA, wb, gb, B_ * T_, C_, C_);

  // scan
  scan_phase1<<<512, blk, 0, stream>>>(kb, vb, td, chunks);
  scan_phase2<<<2048, blk, 0, stream>>>(state0, td, chunks, state_f);
  scan_phase3<<<512, blk, 0, stream>>>(rb, kb, vb, td, tf, chunks, gb, lnw, lnb, mixA);

  // output projection -> d_out
  conv_bf16_kernel<<<convGrid, blk, 0, stream>>>(ow, wb, convN4);
  gemm_bt<float><<<gemmGrid, blk, 0, stream>>>(mixA, wb, out, B_ * T_, C_, C_);
}